// Round 6
// baseline (260.533 us; speedup 1.0000x reference)
//
#include <hip/hip_runtime.h>
#include <stdint.h>

typedef unsigned long long ull;

#define NUM_CLASSES 21
#define NFG 20
#define TOPK 200
#define KPRE 256
#define BS 256                   // 4 waves
#define NV 35                    // ceil(8732/256)
#define CONF_TH 0.01f
#define NMS_TH 0.45f
#define VAR0 0.1f
#define VAR1 0.2f
#define BITS_CONF 0x3C23D70Au    // __float_as_uint(0.01f)
#define BITS_ONE1 0x3F800001u    // just above 1.0f (softmax <= 1)

// One fused kernel: block = (image b, fg class cls). Phase A computes this
// class's softmax scores inline (LDS-staged float4 conf loads; op order
// bit-identical to the previous two-kernel version). Then threshold search,
// gather, sort, decode, NMS, write. No intermediate probs array, no 2nd launch.
__global__ __launch_bounds__(BS) void fused_nms_kernel(
    const float* __restrict__ conf, const float* __restrict__ loc,
    const float* __restrict__ prior, float* __restrict__ out, int B, int P) {

    __shared__ __align__(16) float buf[256 * NUM_CLASSES];  // 21504 B staging
    __shared__ ull arr[2 * KPRE];        // 4 KB
    __shared__ int wsum[2][4][3];
    __shared__ int s_cnt;
    __shared__ float4 sbox[KPRE];        // 4 KB
    __shared__ float sarea[KPRE];        // 1 KB
    __shared__ ull smask[4][KPRE];       // 8 KB, [tile][row]: 8B stride, conflict-free
    __shared__ ull kept[4];
    __shared__ int s_chg[2];

    const int t = threadIdx.x;
    const int lane = t & 63;
    const int wid = t >> 6;              // 0..3
    const ull lmask_lt = (1ULL << lane) - 1ULL;
    const int pair = blockIdx.x;         // b*NFG + (cls-1)
    const int b = pair / NFG;
    const int cls = pair - b * NFG + 1;  // 1..20 (skip background)

    if (t == 0) { s_cnt = 0; s_chg[0] = 0; s_chg[1] = 0; }

    // ---- A: inline softmax for class `cls`, chunk-staged through LDS ----
    unsigned int ubits[NV];
    const float* cbase = conf + (size_t)b * P * NUM_CLASSES;
#pragma unroll 1
    for (int i = 0; i < NV; ++i) {
        const int p0 = i << 8;
        const int cnt = min(256, P - p0);
        const float* src = cbase + (size_t)p0 * NUM_CLASSES;
        if (cnt == 256) {                 // block-uniform branch (barrier-safe)
            const float4* s4 = (const float4*)src;   // 21504B chunks: 16B aligned
            float4* b4 = (float4*)buf;
#pragma unroll
            for (int k = 0; k < 6; ++k) {
                int e = (k << 8) + t;
                if (e < (256 * NUM_CLASSES) / 4) b4[e] = s4[e];
            }
        } else {
            int n = cnt * NUM_CLASSES;
            for (int e = t; e < n; e += 256) buf[e] = src[e];
        }
        __syncthreads();
        unsigned int u = 0u;
        if (t < cnt) {
            const float* row = buf + t * NUM_CLASSES;  // stride 21: conflict-free
            float mx = row[0];
#pragma unroll
            for (int j = 1; j < NUM_CLASSES; ++j) mx = fmaxf(mx, row[j]);
            float s = 0.f, xc = 0.f;
#pragma unroll
            for (int j = 0; j < NUM_CLASSES; ++j) {    // ascending j: match ref ulps
                float e = expf(row[j] - mx);
                s += e;
                if (j == cls) xc = e;
            }
            u = __float_as_uint(xc / s);               // true div: match ref ulps
        }
        ubits[i] = u;
        __syncthreads();                  // buf reused next chunk
    }

    // ---- B: largest T in [0.01,1.0] with count(bits>=T) >= 256; 2 bits/iter ----
    unsigned int lo = BITS_CONF, hi = BITS_ONE1;
    int it = 0;
    while (hi - lo > 1u) {
        unsigned int d = hi - lo;
        unsigned int m1, m2, m3;
        if (d >= 4u) { unsigned int q = d >> 2; m1 = lo + q; m2 = lo + 2 * q; m3 = lo + 3 * q; }
        else { m1 = m2 = m3 = lo + (d >> 1); }
        int c1 = 0, c2 = 0, c3 = 0;
#pragma unroll
        for (int i = 0; i < NV; ++i) {
            unsigned int u = ubits[i];
            c1 += (u >= m1) ? 1 : 0;
            c2 += (u >= m2) ? 1 : 0;
            c3 += (u >= m3) ? 1 : 0;
        }
#pragma unroll
        for (int off = 32; off > 0; off >>= 1) {
            c1 += __shfl_down(c1, off);
            c2 += __shfl_down(c2, off);
            c3 += __shfl_down(c3, off);
        }
        if (lane == 0) {
            wsum[it & 1][wid][0] = c1; wsum[it & 1][wid][1] = c2; wsum[it & 1][wid][2] = c3;
        }
        __syncthreads();
        int t1 = 0, t2 = 0, t3 = 0;
#pragma unroll
        for (int w = 0; w < 4; ++w) {
            t1 += wsum[it & 1][w][0]; t2 += wsum[it & 1][w][1]; t3 += wsum[it & 1][w][2];
        }
        if (t3 >= KPRE) lo = m3;
        else if (t2 >= KPRE) { lo = m2; hi = m3; }
        else if (t1 >= KPRE) { lo = m1; hi = m2; }
        else hi = m1;
        ++it;
    }
    const unsigned int T = lo;

    // ---- C: ballot-compaction gather (cap 512) ----
    int wtot = 0;
#pragma unroll
    for (int i = 0; i < NV; ++i) {
        int p = (i << 8) + t;
        bool pred = (p < P) && (ubits[i] >= T);
        wtot += __popcll(__ballot(pred));
    }
    int wbase = 0;
    if (lane == 0) wbase = atomicAdd(&s_cnt, wtot);
    wbase = __shfl(wbase, 0);
    int run = wbase;
#pragma unroll
    for (int i = 0; i < NV; ++i) {
        int p = (i << 8) + t;
        bool pred = (p < P) && (ubits[i] >= T);
        ull bal = __ballot(pred);
        if (pred) {
            int slot = run + __popcll(bal & lmask_lt);
            if (slot < 2 * KPRE)
                arr[slot] = ((ull)ubits[i] << 32) | (unsigned int)(~p);
        }
        run += __popcll(bal);
    }
    __syncthreads();
    const int nval = min(s_cnt, 2 * KPRE);
    for (int e = t; e < 2 * KPRE; e += KPRE)
        if (e >= nval) arr[e] = 0ULL;
    __syncthreads();

    // ---- D: sort desc; key=(bits<<32)|~idx => value desc, index asc (JAX) ----
    ull key;
    if (nval <= KPRE) {
        key = arr[t];
        for (int kk = 2; kk <= KPRE; kk <<= 1) {
            for (int j = kk >> 1; j > 0; j >>= 1) {
                bool dirDesc = ((t & kk) == 0);
                ull other;
                if (j >= 64) {
                    arr[t] = key;
                    __syncthreads();
                    other = arr[t ^ j];
                    __syncthreads();
                } else {
                    other = __shfl_xor(key, j);
                }
                bool amLow = ((t & j) == 0);
                ull mx = (key > other) ? key : other;
                ull mn = (key > other) ? other : key;
                key = (dirDesc == amLow) ? mx : mn;
            }
        }
    } else {
        // rare tie-overflow path: 512-element LDS bitonic with 256 threads
        for (int kk = 2; kk <= 2 * KPRE; kk <<= 1) {
            for (int j = kk >> 1; j > 0; j >>= 1) {
                for (int e = t; e < 2 * KPRE; e += KPRE) {
                    int ixj = e ^ j;
                    if (ixj > e) {
                        ull a = arr[e], bb = arr[ixj];
                        bool up = ((e & kk) == 0);
                        if (up ? (a < bb) : (a > bb)) { arr[e] = bb; arr[ixj] = a; }
                    }
                }
                __syncthreads();
            }
        }
        key = arr[t];
    }

    // ---- E: decode candidate t ----
    float v = __uint_as_float((unsigned int)(key >> 32));
    int idx = (int)(~(unsigned int)(key & 0xFFFFFFFFu));
    if (idx < 0 || idx >= P) { idx = 0; v = 0.f; }
    const float4 lv = *(const float4*)(loc + ((size_t)b * P + idx) * 4);
    const float4 pv = *(const float4*)(prior + (size_t)idx * 4);
    float cx = pv.x + (lv.x * VAR0) * pv.z;
    float cy = pv.y + (lv.y * VAR0) * pv.w;
    float w = pv.z * expf(lv.z * VAR1);
    float h = pv.w * expf(lv.w * VAR1);
    float x1 = cx - w * 0.5f;
    float y1 = cy - h * 0.5f;
    float x2 = x1 + w;
    float y2 = y1 + h;
    float myarea = fmaxf(x2 - x1, 0.f) * fmaxf(y2 - y1, 0.f);
    sbox[t] = make_float4(x1, y1, x2, y2);
    sarea[t] = myarea;
    __syncthreads();

    // ---- F1: suppression masks, broadcast reads + gated exact-IEEE div.
    // Only tiles tb <= wid are ever consumed (triangular) ----
    {
        const float4 rb = sbox[t];
        const float ra = sarea[t];
#pragma unroll 1
        for (int tb = 0; tb <= wid; ++tb) {
            ull mm = 0ULL;
            for (int ii = 0; ii < 64; ++ii) {
                int g = (tb << 6) + ii;
                float4 gb = sbox[g];     // same addr all lanes => LDS broadcast
                float lx = fmaxf(gb.x, rb.x), ly = fmaxf(gb.y, rb.y);
                float rx = fminf(gb.z, rb.z), ry = fminf(gb.w, rb.w);
                float inter = fmaxf(rx - lx, 0.f) * fmaxf(ry - ly, 0.f);
                bool s = false;
                if (inter > 0.f) {       // skip exact div for disjoint pairs
                    float uni = sarea[g] + ra - inter;
                    s = (inter / fmaxf(uni, 1e-9f)) > NMS_TH;
                }
                mm |= ((ull)(s ? 1u : 0u)) << ii;
            }
            smask[tb][t] = mm;
        }
    }
    __syncthreads();

    // ---- F2: Jacobi fixed-point (converges to exact sequential NMS) ----
    ull m0 = smask[0][t];
    ull m1 = (wid >= 1) ? smask[1][t] : 0ULL;
    ull m2 = (wid >= 2) ? smask[2][t] : 0ULL;
    ull m3 = (wid >= 3) ? smask[3][t] : 0ULL;
    if (wid == 0)      { m0 &= lmask_lt; m1 = 0; m2 = 0; m3 = 0; }
    else if (wid == 1) { m1 &= lmask_lt; m2 = 0; m3 = 0; }
    else if (wid == 2) { m2 &= lmask_lt; m3 = 0; }
    else               { m3 &= lmask_lt; }
    int valid = (v > CONF_TH) ? 1 : 0;
    int alive = valid;
    {
        ull km = __ballot(valid != 0);
        if (lane == 0) kept[wid] = km;
    }
    __syncthreads();
    for (int iter = 0; iter < KPRE; ++iter) {
        ull K0 = kept[0], K1 = kept[1], K2 = kept[2], K3 = kept[3];
        __syncthreads();
        ull dead = (m0 & K0) | (m1 & K1) | (m2 & K2) | (m3 & K3);
        alive = (valid && dead == 0ULL) ? 1 : 0;
        ull km = __ballot(alive != 0);
        ull oldk = (wid == 0) ? K0 : (wid == 1) ? K1 : (wid == 2) ? K2 : K3;
        if (lane == 0 && km != oldk) { kept[wid] = km; s_chg[iter & 1] = 1; }
        if (t == 0) s_chg[(iter & 1) ^ 1] = 0;
        __syncthreads();
        if (s_chg[iter & 1] == 0) break;
    }

    // ---- G: rank via popcounts, write kept rows + zero-fill ----
    {
        ull K0 = kept[0], K1 = kept[1], K2 = kept[2], K3 = kept[3];
        int rank = 0;
        if (wid > 0) rank += __popcll(K0);
        if (wid > 1) rank += __popcll(K1);
        if (wid > 2) rank += __popcll(K2);
        ull ownk = (wid == 0) ? K0 : (wid == 1) ? K1 : (wid == 2) ? K2 : K3;
        rank += __popcll(ownk & lmask_lt);
        int total = __popcll(K0) + __popcll(K1) + __popcll(K2) + __popcll(K3);

        float* orow = out + (size_t)pair * TOPK * 5;
        if (alive && rank < TOPK) {
            float* o = orow + rank * 5;
            o[0] = v; o[1] = x1; o[2] = y1; o[3] = x2; o[4] = y2;
        }
        if (t < TOPK && t >= total) {
            float* o = orow + t * 5;
            o[0] = 0.f; o[1] = 0.f; o[2] = 0.f; o[3] = 0.f; o[4] = 0.f;
        }
    }
}

extern "C" void kernel_launch(void* const* d_in, const int* in_sizes, int n_in,
                              void* d_out, int out_size, void* d_ws, size_t ws_size,
                              hipStream_t stream) {
    const float* loc = (const float*)d_in[0];
    const float* conf = (const float*)d_in[1];
    const float* prior = (const float*)d_in[2];
    float* out = (float*)d_out;

    int P = in_sizes[2] / 4;                // 8732
    int B = in_sizes[0] / (4 * P);          // 32

    fused_nms_kernel<<<B * NFG, BS, 0, stream>>>(conf, loc, prior, out, B, P);
}

// Round 7
// 208.884 us; speedup vs baseline: 1.2473x; 1.2473x over previous
//
#include <hip/hip_runtime.h>
#include <stdint.h>

typedef unsigned long long ull;

#define NUM_CLASSES 21
#define NFG 20
#define TOPK 200
#define KPRE 256
#define BS 256                   // 4 waves
#define NV 35                    // ceil(8732/256)
#define CONF_TH 0.01f
#define NMS_TH 0.45f
#define VAR0 0.1f
#define VAR1 0.2f
#define BITS_CONF 0x3C23D70Au    // __float_as_uint(0.01f)
#define BITS_ONE1 0x3F800001u    // just above 1.0f (softmax <= 1)

// Fused kernel: block = (image b, fg class cls), XCD-swizzled so all 20
// class-blocks of an image share one XCD's L2 (conf slice 0.73 MB; 4 images
// x 0.73 = 2.9 MB < 4 MB L2). Phase A computes the class's softmax scores
// with direct per-thread row loads and spills them to an LDS region (own
// slot only -> no barriers, no scratch); that region is dead after one
// unrolled copy to registers and is aliased by the NMS working set.
__global__ __launch_bounds__(BS) void fused_nms_kernel(
    const float* __restrict__ conf, const float* __restrict__ loc,
    const float* __restrict__ prior, float* __restrict__ out, int B, int P) {

    // 35840 B = max(scores 35*256*4, arr 4K + sbox 4K + sarea 1K + smask 8K)
    __shared__ __align__(16) unsigned char smem[NV * 256 * 4];
    float* scores = (float*)smem;                       // [NV][256]   (phase A)
    ull* arr = (ull*)smem;                              // [512]       (C,D)
    float4* sbox = (float4*)(smem + 4096);              // [256]       (E,F1)
    float* sarea = (float*)(smem + 8192);               // [256]
    ull (*smask)[KPRE] = (ull(*)[KPRE])(smem + 9216);   // [4][256]    (F1,F2)
    __shared__ int wsum[2][4][3];
    __shared__ int s_cnt;
    __shared__ ull kept[4];
    __shared__ int s_chg[2];

    const int t = threadIdx.x;
    const int lane = t & 63;
    const int wid = t >> 6;              // 0..3
    const ull lmask_lt = (1ULL << lane) - 1ULL;

    // XCD swizzle: consecutive blockIdx -> same class, images 0..7 (one per
    // XCD under round-robin dispatch); image b always lands on XCD b%8.
    int pair;
    {
        int blk = blockIdx.x;
        if ((B & 7) == 0) {
            int x = blk & 7;
            int g = blk >> 3;            // 0 .. B*NFG/8-1
            int cls_i = g % NFG;
            int bhi = g / NFG;
            pair = (x + (bhi << 3)) * NFG + cls_i;
        } else {
            pair = blk;
        }
    }
    const int b = pair / NFG;
    const int cls = pair - b * NFG + 1;  // 1..20 (skip background)

    if (t == 0) { s_cnt = 0; s_chg[0] = 0; s_chg[1] = 0; }

    // ---- A: inline softmax for class `cls`; rolled loop, LDS score spill ----
    const float* cbase = conf + (size_t)b * P * NUM_CLASSES;
#pragma unroll 1
    for (int i = 0; i < NV; ++i) {
        int p = (i << 8) + t;
        float sc = 0.f;
        if (p < P) {
            const float* row = cbase + (size_t)p * NUM_CLASSES;
            float x[NUM_CLASSES];
#pragma unroll
            for (int j = 0; j < NUM_CLASSES; ++j) x[j] = row[j];
            float mx = x[0];
#pragma unroll
            for (int j = 1; j < NUM_CLASSES; ++j) mx = fmaxf(mx, x[j]);
            float s = 0.f, xc = 0.f;
#pragma unroll
            for (int j = 0; j < NUM_CLASSES; ++j) {   // ascending j: match ref ulps
                float e = expf(x[j] - mx);
                s += e;
                if (j == cls) xc = e;
            }
            sc = xc / s;                              // true div: match ref ulps
        }
        scores[(i << 8) + t] = sc;   // own slot only: no barrier, no scratch
    }

    // copy to registers with compile-time indices (VGPR-resident, no spill)
    unsigned int ubits[NV];
#pragma unroll
    for (int i = 0; i < NV; ++i)
        ubits[i] = __float_as_uint(scores[(i << 8) + t]);
    // scores region is now dead; B's barriers order it before arr writes in C.

    // ---- B: largest T in [0.01,1] with count(bits>=T) >= 256; 2 bits/iter ----
    unsigned int lo = BITS_CONF, hi = BITS_ONE1;
    int it = 0;
    while (hi - lo > 1u) {
        unsigned int d = hi - lo;
        unsigned int m1, m2, m3;
        if (d >= 4u) { unsigned int q = d >> 2; m1 = lo + q; m2 = lo + 2 * q; m3 = lo + 3 * q; }
        else { m1 = m2 = m3 = lo + (d >> 1); }
        int c1 = 0, c2 = 0, c3 = 0;
#pragma unroll
        for (int i = 0; i < NV; ++i) {
            unsigned int u = ubits[i];
            c1 += (u >= m1) ? 1 : 0;
            c2 += (u >= m2) ? 1 : 0;
            c3 += (u >= m3) ? 1 : 0;
        }
#pragma unroll
        for (int off = 32; off > 0; off >>= 1) {
            c1 += __shfl_down(c1, off);
            c2 += __shfl_down(c2, off);
            c3 += __shfl_down(c3, off);
        }
        if (lane == 0) {
            wsum[it & 1][wid][0] = c1; wsum[it & 1][wid][1] = c2; wsum[it & 1][wid][2] = c3;
        }
        __syncthreads();
        int t1 = 0, t2 = 0, t3 = 0;
#pragma unroll
        for (int w = 0; w < 4; ++w) {
            t1 += wsum[it & 1][w][0]; t2 += wsum[it & 1][w][1]; t3 += wsum[it & 1][w][2];
        }
        if (t3 >= KPRE) lo = m3;
        else if (t2 >= KPRE) { lo = m2; hi = m3; }
        else if (t1 >= KPRE) { lo = m1; hi = m2; }
        else hi = m1;
        ++it;
    }
    const unsigned int T = lo;

    // ---- C: ballot-compaction gather (cap 512) ----
    int wtot = 0;
#pragma unroll
    for (int i = 0; i < NV; ++i) {
        int p = (i << 8) + t;
        bool pred = (p < P) && (ubits[i] >= T);
        wtot += __popcll(__ballot(pred));
    }
    int wbase = 0;
    if (lane == 0) wbase = atomicAdd(&s_cnt, wtot);
    wbase = __shfl(wbase, 0);
    int run = wbase;
#pragma unroll
    for (int i = 0; i < NV; ++i) {
        int p = (i << 8) + t;
        bool pred = (p < P) && (ubits[i] >= T);
        ull bal = __ballot(pred);
        if (pred) {
            int slot = run + __popcll(bal & lmask_lt);
            if (slot < 2 * KPRE)
                arr[slot] = ((ull)ubits[i] << 32) | (unsigned int)(~p);
        }
        run += __popcll(bal);
    }
    __syncthreads();
    const int nval = min(s_cnt, 2 * KPRE);
    for (int e = t; e < 2 * KPRE; e += KPRE)
        if (e >= nval) arr[e] = 0ULL;
    __syncthreads();

    // ---- D: sort desc; key=(bits<<32)|~idx => value desc, index asc (JAX) ----
    ull key;
    if (nval <= KPRE) {
        key = arr[t];
        for (int kk = 2; kk <= KPRE; kk <<= 1) {
            for (int j = kk >> 1; j > 0; j >>= 1) {
                bool dirDesc = ((t & kk) == 0);
                ull other;
                if (j >= 64) {
                    arr[t] = key;
                    __syncthreads();
                    other = arr[t ^ j];
                    __syncthreads();
                } else {
                    other = __shfl_xor(key, j);
                }
                bool amLow = ((t & j) == 0);
                ull mx = (key > other) ? key : other;
                ull mn = (key > other) ? other : key;
                key = (dirDesc == amLow) ? mx : mn;
            }
        }
    } else {
        // rare tie-overflow path: 512-element LDS bitonic with 256 threads
        for (int kk = 2; kk <= 2 * KPRE; kk <<= 1) {
            for (int j = kk >> 1; j > 0; j >>= 1) {
                for (int e = t; e < 2 * KPRE; e += KPRE) {
                    int ixj = e ^ j;
                    if (ixj > e) {
                        ull a = arr[e], bb = arr[ixj];
                        bool up = ((e & kk) == 0);
                        if (up ? (a < bb) : (a > bb)) { arr[e] = bb; arr[ixj] = a; }
                    }
                }
                __syncthreads();
            }
        }
        key = arr[t];
    }

    // ---- E: decode candidate t ----
    float v = __uint_as_float((unsigned int)(key >> 32));
    int idx = (int)(~(unsigned int)(key & 0xFFFFFFFFu));
    if (idx < 0 || idx >= P) { idx = 0; v = 0.f; }
    const float4 lv = *(const float4*)(loc + ((size_t)b * P + idx) * 4);
    const float4 pv = *(const float4*)(prior + (size_t)idx * 4);
    float cx = pv.x + (lv.x * VAR0) * pv.z;
    float cy = pv.y + (lv.y * VAR0) * pv.w;
    float w = pv.z * expf(lv.z * VAR1);
    float h = pv.w * expf(lv.w * VAR1);
    float x1 = cx - w * 0.5f;
    float y1 = cy - h * 0.5f;
    float x2 = x1 + w;
    float y2 = y1 + h;
    float myarea = fmaxf(x2 - x1, 0.f) * fmaxf(y2 - y1, 0.f);
    sbox[t] = make_float4(x1, y1, x2, y2);
    sarea[t] = myarea;
    __syncthreads();

    // ---- F1: suppression masks, balanced (3 tiles max/wave), broadcast g,
    // gated exact-IEEE div, smask[tile][row] -> conflict-free ----
#pragma unroll
    for (int k = 0; k < 3; ++k) {
        int tid = wid + (k << 2);
        if (tid < 10) {
            int rblk, tb;
            if (tid >= 6)      { rblk = 3; tb = tid - 6; }
            else if (tid >= 3) { rblk = 2; tb = tid - 3; }
            else if (tid >= 1) { rblk = 1; tb = tid - 1; }
            else               { rblk = 0; tb = 0; }
            int r = (rblk << 6) + lane;
            float4 rb = sbox[r];
            float ra = sarea[r];
            ull mm = 0ULL;
            for (int ii = 0; ii < 64; ++ii) {
                int g = (tb << 6) + ii;
                float4 gb = sbox[g];     // lane-uniform addr => LDS broadcast
                float lx = fmaxf(gb.x, rb.x), ly = fmaxf(gb.y, rb.y);
                float rx = fminf(gb.z, rb.z), ry = fminf(gb.w, rb.w);
                float inter = fmaxf(rx - lx, 0.f) * fmaxf(ry - ly, 0.f);
                bool s = false;
                if (inter > 0.f) {       // skip exact div for disjoint pairs
                    float uni = sarea[g] + ra - inter;
                    s = (inter / fmaxf(uni, 1e-9f)) > NMS_TH;
                }
                mm |= ((ull)(s ? 1u : 0u)) << ii;
            }
            smask[tb][r] = mm;
        }
    }
    __syncthreads();

    // ---- F2: Jacobi fixed-point (converges to exact sequential NMS) ----
    ull m0 = smask[0][t];
    ull m1 = (wid >= 1) ? smask[1][t] : 0ULL;
    ull m2 = (wid >= 2) ? smask[2][t] : 0ULL;
    ull m3 = (wid >= 3) ? smask[3][t] : 0ULL;
    if (wid == 0)      { m0 &= lmask_lt; m1 = 0; m2 = 0; m3 = 0; }
    else if (wid == 1) { m1 &= lmask_lt; m2 = 0; m3 = 0; }
    else if (wid == 2) { m2 &= lmask_lt; m3 = 0; }
    else               { m3 &= lmask_lt; }
    int valid = (v > CONF_TH) ? 1 : 0;
    int alive = valid;
    {
        ull km = __ballot(valid != 0);
        if (lane == 0) kept[wid] = km;
    }
    __syncthreads();
    for (int iter = 0; iter < KPRE; ++iter) {
        ull K0 = kept[0], K1 = kept[1], K2 = kept[2], K3 = kept[3];
        __syncthreads();
        ull dead = (m0 & K0) | (m1 & K1) | (m2 & K2) | (m3 & K3);
        alive = (valid && dead == 0ULL) ? 1 : 0;
        ull km = __ballot(alive != 0);
        ull oldk = (wid == 0) ? K0 : (wid == 1) ? K1 : (wid == 2) ? K2 : K3;
        if (lane == 0 && km != oldk) { kept[wid] = km; s_chg[iter & 1] = 1; }
        if (t == 0) s_chg[(iter & 1) ^ 1] = 0;
        __syncthreads();
        if (s_chg[iter & 1] == 0) break;
    }

    // ---- G: rank via popcounts, write kept rows + zero-fill ----
    {
        ull K0 = kept[0], K1 = kept[1], K2 = kept[2], K3 = kept[3];
        int rank = 0;
        if (wid > 0) rank += __popcll(K0);
        if (wid > 1) rank += __popcll(K1);
        if (wid > 2) rank += __popcll(K2);
        ull ownk = (wid == 0) ? K0 : (wid == 1) ? K1 : (wid == 2) ? K2 : K3;
        rank += __popcll(ownk & lmask_lt);
        int total = __popcll(K0) + __popcll(K1) + __popcll(K2) + __popcll(K3);

        float* orow = out + (size_t)pair * TOPK * 5;
        if (alive && rank < TOPK) {
            float* o = orow + rank * 5;
            o[0] = v; o[1] = x1; o[2] = y1; o[3] = x2; o[4] = y2;
        }
        if (t < TOPK && t >= total) {
            float* o = orow + t * 5;
            o[0] = 0.f; o[1] = 0.f; o[2] = 0.f; o[3] = 0.f; o[4] = 0.f;
        }
    }
}

extern "C" void kernel_launch(void* const* d_in, const int* in_sizes, int n_in,
                              void* d_out, int out_size, void* d_ws, size_t ws_size,
                              hipStream_t stream) {
    const float* loc = (const float*)d_in[0];
    const float* conf = (const float*)d_in[1];
    const float* prior = (const float*)d_in[2];
    float* out = (float*)d_out;

    int P = in_sizes[2] / 4;                // 8732
    int B = in_sizes[0] / (4 * P);          // 32

    fused_nms_kernel<<<B * NFG, BS, 0, stream>>>(conf, loc, prior, out, B, P);
}